// Round 7
// baseline (85.406 us; speedup 1.0000x reference)
//
#include <hip/hip_runtime.h>
#include <cmath>

#define T_DIM 2048
#define B_DIM 8
#define C_DIM 1024
#define H_DIM 8
#define R_DIM 128
#define BH_DIM 64          // B*H
#define COLS 8192          // BH*R
#define COL4 2048          // COLS/4
#define NCH 64             // scan chunks
#define LT 32              // T per chunk
__device__ __constant__ float INV_K = 0.33333333333333333f;

typedef _Float16 h4 __attribute__((ext_vector_type(4)));
typedef _Float16 h8 __attribute__((ext_vector_type(8)));

// ---- Kernel A: fused offsets GEMM + per-chunk column sums (ONE x read) ----
// Grid 512 = 8 col-groups (== batch b) x 64 t-chunks. Register prefetch of
// the next g-group's 4 x rows hides HBM latency under the FMA+fold work.
__global__ __launch_bounds__(256, 2) void offcsum_kernel(
        const float4* __restrict__ x4, const float* __restrict__ W,
        const float* __restrict__ bias, float* __restrict__ off,
        float4* __restrict__ csum4) {
    __shared__ float Wt[16 * 1024];          // 64 KB
    __shared__ float sdata[4][8][64];        // 8 KB
    const int bid = blockIdx.x;
    const int cg = bid >> 6;                 // 0..7  == batch index b
    const int ch = bid & 63;                 // 0..63 == t chunk
    const int tid = threadIdx.x;
    const int wave = tid >> 6, lane = tid & 63;
    const int col4 = cg * 256 + tid;         // global col4 in [0, 2048)

    const float4* xp = x4 + (size_t)(ch * LT) * COL4 + col4;
    // issue first group's loads before LDS staging so they overlap
    float4 xv0 = xp[0];
    float4 xv1 = xp[(size_t)1 * COL4];
    float4 xv2 = xp[(size_t)2 * COL4];
    float4 xv3 = xp[(size_t)3 * COL4];

    for (int idx = tid; idx < 4096; idx += 256) {
        int c = idx >> 2, j4 = (idx & 3) * 4;
        float4 w = *reinterpret_cast<const float4*>(W + c * 16 + j4);
        Wt[(j4 + 0) * 1024 + c] = w.x;
        Wt[(j4 + 1) * 1024 + c] = w.y;
        Wt[(j4 + 2) * 1024 + c] = w.z;
        Wt[(j4 + 3) * 1024 + c] = w.w;
    }
    __syncthreads();

    const int cbase = tid * 4;
    float csx = 0.f, csy = 0.f, csz = 0.f, csw = 0.f;

#pragma unroll 1
    for (int g = 0; g < 8; ++g) {
        float4 c0 = xv0, c1 = xv1, c2 = xv2, c3 = xv3;
        if (g < 7) {                         // prefetch next group
            const float4* np = xp + (size_t)((g + 1) * 4) * COL4;
            xv0 = np[0];
            xv1 = np[(size_t)1 * COL4];
            xv2 = np[(size_t)2 * COL4];
            xv3 = np[(size_t)3 * COL4];
        }
        float acc[64];
#pragma unroll
        for (int i = 0; i < 64; ++i) acc[i] = 0.f;
#pragma unroll
        for (int j = 0; j < 16; ++j) {
            float4 w = *reinterpret_cast<const float4*>(&Wt[j * 1024 + cbase]);
            acc[j]      = fmaf(c0.x, w.x, fmaf(c0.y, w.y, fmaf(c0.z, w.z, fmaf(c0.w, w.w, acc[j]))));
            acc[16 + j] = fmaf(c1.x, w.x, fmaf(c1.y, w.y, fmaf(c1.z, w.z, fmaf(c1.w, w.w, acc[16 + j]))));
            acc[32 + j] = fmaf(c2.x, w.x, fmaf(c2.y, w.y, fmaf(c2.z, w.z, fmaf(c2.w, w.w, acc[32 + j]))));
            acc[48 + j] = fmaf(c3.x, w.x, fmaf(c3.y, w.y, fmaf(c3.z, w.z, fmaf(c3.w, w.w, acc[48 + j]))));
        }
        csx += c0.x + c1.x + c2.x + c3.x;
        csy += c0.y + c1.y + c2.y + c3.y;
        csz += c0.z + c1.z + c2.z + c3.z;
        csw += c0.w + c1.w + c2.w + c3.w;
        // value-folding wave reduction: lane l ends with value (tl<<4)|j
#pragma unroll
        for (int m = 32; m >= 1; m >>= 1) {
            bool hi = (lane & m) != 0;
#pragma unroll
            for (int i = 0; i < m; ++i) {
                float send = hi ? acc[i] : acc[i + m];
                float recv = __shfl_xor(send, m, 64);
                acc[i] = (hi ? acc[i + m] : acc[i]) + recv;
            }
        }
        sdata[wave][g][lane] = acc[0];
    }

    float4 agg; agg.x = csx * INV_K; agg.y = csy * INV_K; agg.z = csz * INV_K; agg.w = csw * INV_K;
    csum4[(size_t)ch * COL4 + col4] = agg;

    __syncthreads();
#pragma unroll
    for (int i = 0; i < 2; ++i) {
        int idx = tid + i * 256;
        int g = idx >> 6, l = idx & 63;
        int tl = l >> 4, j = l & 15;
        float s = sdata[0][g][l] + sdata[1][g][l] + sdata[2][g][l] + sdata[3][g][l];
        s += bias[j];
        int t = ch * LT + g * 4 + tl;
        off[((size_t)t * B_DIM + cg) * 16 + j] = 1.f / (1.f + expf(-s));
    }
}

// ---- Kernel B: scan within chunk, fp32 accum, fp16 store (round-4 proven) ----
__global__ void scan_kernel(const float4* __restrict__ x4, const float4* __restrict__ csum4,
                            _Float16* __restrict__ S) {
    int gid = blockIdx.x * 256 + threadIdx.x;
    int chunk = gid >> 11;                      // uniform within block
    int col4 = gid & (COL4 - 1);
    float rx = 0.f, ry = 0.f, rz = 0.f, rw = 0.f;
    for (int c = 0; c < chunk; ++c) {           // csum is 2MB -> L2-hot
        float4 v = csum4[c * COL4 + col4];
        rx += v.x; ry += v.y; rz += v.z; rw += v.w;
    }
    const float4* xp = x4 + (size_t)chunk * LT * COL4 + col4;
    _Float16* Sp = S + (size_t)chunk * LT * COLS + col4 * 4;
#pragma unroll 4
    for (int t = 0; t < LT; ++t) {
        float4 v = xp[(size_t)t * COL4];
        rx = fmaf(v.x, INV_K, rx);
        ry = fmaf(v.y, INV_K, ry);
        rz = fmaf(v.z, INV_K, rz);
        rw = fmaf(v.w, INV_K, rw);
        h4 o; o.x = (_Float16)rx; o.y = (_Float16)ry; o.z = (_Float16)rz; o.w = (_Float16)rw;
        *reinterpret_cast<h4*>(Sp + (size_t)t * COLS) = o;   // coalesced 8B/lane
    }
}

// ---- Kernel C: gather, 32 outputs/thread => 16 independent S loads (MLP) ----
// One block per t (2048 blocks, bijective XCD swizzle). Thread (bh, r32)
// loads 4 rows x 4 h8-chunks (imm-offset folded), interps, 8 float4 stores.
__global__ __launch_bounds__(256) void gather_kernel(
        const _Float16* __restrict__ S, const float* __restrict__ off,
        float* __restrict__ out) {
    int bid = blockIdx.x;
    int t = ((bid & 7) << 8) | (bid >> 3);      // bijective: 2048 % 8 == 0
    int tid = threadIdx.x;
    int bh = tid >> 2;
    int r32 = (tid & 3) << 5;
    int b = bh >> 3, h = bh & 7;
    const float* o = off + ((size_t)t * B_DIM + b) * 16;
    float aL = o[h], aR = o[8 + h];
    float tf = (float)t;
    float lenL = 1.f + aL * fmaxf(tf - 1.f, 0.f);
    float lenR = 1.f + aR * fmaxf((float)(T_DIM - 1) - tf - 1.f, 0.f);
    float fL = fmaxf(tf - lenL - 1.f, -1.f);
    float fR = fminf(tf + lenR, (float)(T_DIM - 1));
    float ffL = floorf(fL); int i0L = (int)ffL; float frL = fL - ffL;
    float ffR = floorf(fR); int i0R = (int)ffR; float frR = fR - ffR;
    int i0Lc = min(max(i0L, 0), T_DIM - 1), i1Lc = min(i0L + 1, T_DIM - 1);
    int i0Rc = min(max(i0R, 0), T_DIM - 1), i1Rc = min(i0R + 1, T_DIM - 1);
    int col = (bh << 7) | r32;

    const h8* p0L = reinterpret_cast<const h8*>(S + (size_t)i0Lc * COLS + col);
    const h8* p1L = reinterpret_cast<const h8*>(S + (size_t)i1Lc * COLS + col);
    const h8* p0R = reinterpret_cast<const h8*>(S + (size_t)i0Rc * COLS + col);
    const h8* p1R = reinterpret_cast<const h8*>(S + (size_t)i1Rc * COLS + col);
    const h8 zero8 = {0, 0, 0, 0, 0, 0, 0, 0};
    bool mL = (i0L >= 0), mR = (i0R >= 0);

    h8 a1[4], a0[4], b1[4], b0[4];
#pragma unroll
    for (int k = 0; k < 4; ++k) a1[k] = p1R[k];
#pragma unroll
    for (int k = 0; k < 4; ++k) b1[k] = p1L[k];
#pragma unroll
    for (int k = 0; k < 4; ++k) a0[k] = mR ? p0R[k] : zero8;
#pragma unroll
    for (int k = 0; k < 4; ++k) b0[k] = mL ? p0L[k] : zero8;

    float* op = out + (size_t)t * COLS + col;
#pragma unroll
    for (int k = 0; k < 4; ++k) {
        float r8[8];
#pragma unroll
        for (int i = 0; i < 8; ++i) {
            float x0 = (float)a0[k][i], x1 = (float)a1[k][i];
            float y0 = (float)b0[k][i], y1 = (float)b1[k][i];
            r8[i] = fmaf(frR, x1 - x0, x0) - fmaf(frL, y1 - y0, y0);
        }
        *reinterpret_cast<float4*>(op + k * 8)     = make_float4(r8[0], r8[1], r8[2], r8[3]);
        *reinterpret_cast<float4*>(op + k * 8 + 4) = make_float4(r8[4], r8[5], r8[6], r8[7]);
    }
}

extern "C" void kernel_launch(void* const* d_in, const int* in_sizes, int n_in,
                              void* d_out, int out_size, void* d_ws, size_t ws_size,
                              hipStream_t stream) {
    const float4* x4 = (const float4*)d_in[0];
    const float* W  = (const float*)d_in[1];
    const float* bi = (const float*)d_in[2];

    char* ws = (char*)d_ws;
    const size_t S_bytes   = (size_t)T_DIM * COLS * sizeof(_Float16);    // 32 MB
    const size_t off_bytes = (size_t)T_DIM * B_DIM * 16 * sizeof(float); // 1 MB
    _Float16* S = (_Float16*)ws;
    float* off  = (float*)(ws + S_bytes);
    float* csum = (float*)(ws + S_bytes + off_bytes);                    // 2 MB

    offcsum_kernel<<<512, 256, 0, stream>>>(x4, W, bi, off, (float4*)csum);
    scan_kernel<<<(NCH * COL4) / 256, 256, 0, stream>>>(
        x4, (const float4*)csum, S);
    gather_kernel<<<T_DIM, 256, 0, stream>>>(S, off, (float*)d_out);
}